// Round 9
// baseline (152.571 us; speedup 1.0000x reference)
//
#include <hip/hip_runtime.h>
#include <hip/hip_bf16.h>

#define N_NODES 100000
#define N_EDGES 1600000
#define D 128
#define TILES (N_NODES / 16)   // 6250 row-tiles of 16
#define WPB 8                  // waves per block in fused kernel
#define NB2 782                // buckets of 128 nodes (ceil(100000/128))
#define NPB2 128               // nodes per bucket
#define CAP 4096               // edge capacity per bucket (mean 2046, ~45 sigma)
#define EPB 8192               // edges per partition block
#define PBLK 196               // ceil(1600000/8192)
#define CVTB 6250              // cvt blocks in fuseA
#define PREPB 128              // prepw blocks in fuseA

typedef __attribute__((ext_vector_type(4))) float f32x4;
typedef __attribute__((ext_vector_type(8))) short short8;
typedef __attribute__((ext_vector_type(4))) unsigned int u32x4;
typedef __attribute__((ext_vector_type(2))) unsigned int u32x2;

// f32 -> bf16 round-to-nearest-even
static __device__ __forceinline__ unsigned short f2bf(float f) {
  unsigned u = __float_as_uint(f);
  u += 0x7fffu + ((u >> 16) & 1u);
  return (unsigned short)(u >> 16);
}

static __device__ __forceinline__ void acc4(u32x2 u, float& a0, float& a1,
                                            float& a2, float& a3) {
  a0 += __uint_as_float(u[0] << 16);
  a1 += __uint_as_float(u[0] & 0xffff0000u);
  a2 += __uint_as_float(u[1] << 16);
  a3 += __uint_as_float(u[1] & 0xffff0000u);
}

// ---- fuseA: cvt (x->bf16) | p3b (fixed-cap partition) | prepw (W prep) ----
// Three independent preprocessing stages in ONE dispatch, disjoint blockIdx.
__global__ __launch_bounds__(256) void fuseA_k(
    const float* __restrict__ x, unsigned* __restrict__ xh,
    const int* __restrict__ ei, int* __restrict__ btail,
    unsigned* __restrict__ part, const float* __restrict__ Wl,
    const float* __restrict__ Wr, unsigned short* __restrict__ wt_g) {
  __shared__ int bh[NB2], lbase[NB2], lcur[NB2];
  int t = threadIdx.x;
  if (blockIdx.x < CVTB) {
    // ---- cvt: 8 floats -> 4 packed bf16x2 per thread ----
    size_t i = (size_t)blockIdx.x * 256 + t;
    const f32x4* p = (const f32x4*)(x + i * 8);
    f32x4 v0 = p[0], v1 = p[1];
    u32x4 o;
    o[0] = ((unsigned)f2bf(v0[1]) << 16) | f2bf(v0[0]);
    o[1] = ((unsigned)f2bf(v0[3]) << 16) | f2bf(v0[2]);
    o[2] = ((unsigned)f2bf(v1[1]) << 16) | f2bf(v1[0]);
    o[3] = ((unsigned)f2bf(v1[3]) << 16) | f2bf(v1[2]);
    *(u32x4*)(xh + i * 4) = o;
    return;
  }
  if (blockIdx.x >= CVTB + PBLK) {
    // ---- prepw: W -> bf16 in physical swizzled layout ----
    int i = (blockIdx.x - CVTB - PBLK) * 256 + t;  // 0..32767
    int k = i >> 7, c = i & 127;
    float w = (k < 128) ? Wl[k * 128 + c] : Wr[(k - 128) * 128 + c];
    int phys = (k >> 3) ^ (c & 7);
    wt_g[c * 256 + (phys << 3) + (k & 7)] = f2bf(w);
    return;
  }
  // ---- p3b: partition edges into fixed-cap bucket regions ----
  // code = (dst & 127) << 17 | src  (24 bits)
  for (int i = t; i < NB2; i += 256) { bh[i] = 0; lcur[i] = 0; }
  __syncthreads();
  int base = (blockIdx.x - CVTB) * EPB;
  int end = min(base + EPB, N_EDGES);
  for (int i = base + t; i < end; i += 256)
    atomicAdd(&bh[ei[N_EDGES + i] >> 7], 1);
  __syncthreads();
  for (int i = t; i < NB2; i += 256)
    if (bh[i]) lbase[i] = atomicAdd(&btail[i], bh[i]);
  __syncthreads();
  for (int i = base + t; i < end; i += 256) {
    int dst = ei[N_EDGES + i];
    int src = ei[i];
    int b = dst >> 7;
    int pos = lbase[b] + atomicAdd(&lcur[b], 1);
    if (pos < CAP)
      part[(size_t)b * CAP + pos] =
          ((unsigned)(dst & (NPB2 - 1)) << 17) | (unsigned)src;
  }
}

// ---- p4c: per-bucket CSR build. Stages codes in LDS, writes per-node
// (beg,deg) and the CSR IN PLACE over the part region. ----
__global__ __launch_bounds__(512) void p4c_k(unsigned* __restrict__ part,
                                             const int* __restrict__ btail,
                                             int2* __restrict__ pd) {
  __shared__ unsigned s_codes[CAP];  // 16 KiB
  __shared__ int s_deg[NPB2], s_scan[NPB2], s_off[NPB2];
  int t = threadIdx.x, b = blockIdx.x;
  int ne = min(btail[b], CAP);
  unsigned* pp = part + (size_t)b * CAP;
  for (int i = t; i < ne; i += 512) s_codes[i] = pp[i];
  if (t < NPB2) s_deg[t] = 0;
  __syncthreads();
  for (int i = t; i < ne; i += 512) atomicAdd(&s_deg[s_codes[i] >> 17], 1);
  __syncthreads();
  if (t < NPB2) s_scan[t] = s_deg[t];
  __syncthreads();
  for (int o = 1; o < NPB2; o <<= 1) {  // inclusive scan over 128 counts
    int u = (t >= o && t < NPB2) ? s_scan[t - o] : 0;
    __syncthreads();
    if (t < NPB2) s_scan[t] += u;
    __syncthreads();
  }
  if (t < NPB2) {
    int deg = s_deg[t];
    int ex = s_scan[t] - deg;
    s_off[t] = ex;
    int node = b * NPB2 + t;
    if (node < N_NODES) {
      int2 v;
      v.x = b * CAP + ex;
      v.y = deg;
      pd[node] = v;
    }
  }
  __syncthreads();
  for (int i = t; i < ne; i += 512) {
    unsigned c = s_codes[i];
    int pos = atomicAdd(&s_off[c >> 17], 1);
    pp[pos] = c & 0x1FFFFu;  // csr overwrites part region (staged in LDS)
  }
}

// ---- Gather: 2 nodes/wave, 32 lanes x 4 dims, 8-deep MLP ----
__global__ __launch_bounds__(256) void gather2_k(const unsigned* __restrict__ xh,
                                                 const unsigned* __restrict__ csr,
                                                 const int2* __restrict__ pd,
                                                 unsigned* __restrict__ mh) {
  int wid = (blockIdx.x * 256 + threadIdx.x) >> 6;
  int lane = threadIdx.x & 63;
  int half = lane >> 5, lh = lane & 31;
  int node = wid * 2 + half;
  if (node >= N_NODES) return;
  int2 v = pd[node];
  int base = v.x;
  int deg = v.y;
  float a0 = 0.f, a1 = 0.f, a2 = 0.f, a3 = 0.f;
  float b0 = 0.f, b1 = 0.f, b2 = 0.f, b3 = 0.f;
  for (int c = 0; c < deg; c += 32) {
    int rem = deg - c;
    int n = min(32, rem);
    int eidx = (lh < rem) ? (int)csr[base + c + lh] : 0;
    int j = 0;
    for (; j + 7 < n; j += 8) {
      int s0 = __shfl(eidx, j, 32);
      int s1 = __shfl(eidx, j + 1, 32);
      int s2 = __shfl(eidx, j + 2, 32);
      int s3 = __shfl(eidx, j + 3, 32);
      int s4 = __shfl(eidx, j + 4, 32);
      int s5 = __shfl(eidx, j + 5, 32);
      int s6 = __shfl(eidx, j + 6, 32);
      int s7 = __shfl(eidx, j + 7, 32);
      u32x2 u0 = *(const u32x2*)(xh + (size_t)s0 * 64 + lh * 2);
      u32x2 u1 = *(const u32x2*)(xh + (size_t)s1 * 64 + lh * 2);
      u32x2 u2 = *(const u32x2*)(xh + (size_t)s2 * 64 + lh * 2);
      u32x2 u3 = *(const u32x2*)(xh + (size_t)s3 * 64 + lh * 2);
      u32x2 u4 = *(const u32x2*)(xh + (size_t)s4 * 64 + lh * 2);
      u32x2 u5 = *(const u32x2*)(xh + (size_t)s5 * 64 + lh * 2);
      u32x2 u6 = *(const u32x2*)(xh + (size_t)s6 * 64 + lh * 2);
      u32x2 u7 = *(const u32x2*)(xh + (size_t)s7 * 64 + lh * 2);
      acc4(u0, a0, a1, a2, a3);
      acc4(u1, b0, b1, b2, b3);
      acc4(u2, a0, a1, a2, a3);
      acc4(u3, b0, b1, b2, b3);
      acc4(u4, a0, a1, a2, a3);
      acc4(u5, b0, b1, b2, b3);
      acc4(u6, a0, a1, a2, a3);
      acc4(u7, b0, b1, b2, b3);
    }
    for (; j + 3 < n; j += 4) {
      int s0 = __shfl(eidx, j, 32);
      int s1 = __shfl(eidx, j + 1, 32);
      int s2 = __shfl(eidx, j + 2, 32);
      int s3 = __shfl(eidx, j + 3, 32);
      u32x2 u0 = *(const u32x2*)(xh + (size_t)s0 * 64 + lh * 2);
      u32x2 u1 = *(const u32x2*)(xh + (size_t)s1 * 64 + lh * 2);
      u32x2 u2 = *(const u32x2*)(xh + (size_t)s2 * 64 + lh * 2);
      u32x2 u3 = *(const u32x2*)(xh + (size_t)s3 * 64 + lh * 2);
      acc4(u0, a0, a1, a2, a3);
      acc4(u1, b0, b1, b2, b3);
      acc4(u2, a0, a1, a2, a3);
      acc4(u3, b0, b1, b2, b3);
    }
    for (; j < n; j++) {
      int s0 = __shfl(eidx, j, 32);
      u32x2 u0 = *(const u32x2*)(xh + (size_t)s0 * 64 + lh * 2);
      acc4(u0, a0, a1, a2, a3);
    }
  }
  float inv = 1.0f / fmaxf((float)deg, 1.0f);
  a0 = (a0 + b0) * inv;
  a1 = (a1 + b1) * inv;
  a2 = (a2 + b2) * inv;
  a3 = (a3 + b3) * inv;
  u32x2 o;
  o[0] = ((unsigned)f2bf(a1) << 16) | f2bf(a0);
  o[1] = ((unsigned)f2bf(a3) << 16) | f2bf(a2);
  *(u32x2*)(mh + (size_t)node * 64 + lh * 2) = o;
}

// ---- Fused: out = normalize( [mean | x] @ [W_l; W_r] + b_l ), bf16 MFMA ----
__global__ __launch_bounds__(512) void fused_k(
    const unsigned* __restrict__ xh, const unsigned* __restrict__ mh,
    const unsigned* __restrict__ wt_g, const float* __restrict__ bl,
    float* __restrict__ out) {
  __shared__ unsigned Wt[16384];  // 64 KiB as u32 (32768 bf16)

  int tid = threadIdx.x;
  {
    const u32x4* src = (const u32x4*)wt_g;
    u32x4* dst = (u32x4*)Wt;
    #pragma unroll
    for (int it = 0; it < 8; it++) dst[it * 512 + tid] = src[it * 512 + tid];
  }
  __syncthreads();

  int tile = blockIdx.x * WPB + (tid >> 6);
  if (tile >= TILES) return;
  int lane = tid & 63;
  int c0 = lane & 15;  // A-row within tile / D-column-within-16
  int g = lane >> 4;   // k-group selector
  int row0 = tile * 16;
  const unsigned short* Wt16 = (const unsigned short*)Wt;

  f32x4 acc[8];
  #pragma unroll
  for (int ct = 0; ct < 8; ct++)
    for (int j = 0; j < 4; j++) acc[ct][j] = 0.0f;

  #pragma unroll
  for (int kf = 0; kf < 8; kf++) {
    int koff = (kf & 3) * 32 + g * 8;
    const unsigned short* a_src = (const unsigned short*)((kf < 4) ? mh : xh);
    short8 af = *(const short8*)(a_src + (size_t)(row0 + c0) * D + koff);
    #pragma unroll
    for (int ct = 0; ct < 8; ct++) {
      int c = ct * 16 + c0;
      short8 bf = *(const short8*)&Wt16[c * 256 + ((((kf << 2) + g) ^ (c & 7)) << 3)];
      acc[ct] = __builtin_amdgcn_mfma_f32_16x16x32_bf16(af, bf, acc[ct], 0, 0, 0);
    }
  }

  float ss[4] = {0.f, 0.f, 0.f, 0.f};
  #pragma unroll
  for (int ct = 0; ct < 8; ct++) {
    float bias = bl[ct * 16 + c0];
    #pragma unroll
    for (int j = 0; j < 4; j++) {
      float v = acc[ct][j] + bias;
      acc[ct][j] = v;
      ss[j] += v * v;
    }
  }
  #pragma unroll
  for (int j = 0; j < 4; j++) {
    float s = ss[j];
    s += __shfl_xor(s, 1);
    s += __shfl_xor(s, 2);
    s += __shfl_xor(s, 4);
    s += __shfl_xor(s, 8);
    ss[j] = 1.0f / fmaxf(sqrtf(s), 1e-12f);
  }
  #pragma unroll
  for (int ct = 0; ct < 8; ct++) {
    #pragma unroll
    for (int j = 0; j < 4; j++) {
      out[(size_t)(row0 + g * 4 + j) * D + ct * 16 + c0] = acc[ct][j] * ss[j];
    }
  }
}

extern "C" void kernel_launch(void* const* d_in, const int* in_sizes, int n_in,
                              void* d_out, int out_size, void* d_ws, size_t ws_size,
                              hipStream_t stream) {
  const float* x  = (const float*)d_in[0];
  const int*   ei = (const int*)d_in[1];
  const float* Wl = (const float*)d_in[2];
  const float* bl = (const float*)d_in[3];
  const float* Wr = (const float*)d_in[4];
  float* out = (float*)d_out;

  // Workspace layout (int elements)
  int* w = (int*)d_ws;
  int* btail = w;                               // 782 (pad to 800)
  int2* pd = (int2*)(w + 800);                  // 100000 int2 = 200000 ints
  unsigned* part = (unsigned*)(w + 200800);     // 782*4096 = 3203072 (12.8 MB)
  unsigned short* wt_g = (unsigned short*)(w + 3403872);  // 32768 u16
  const size_t XH_OFF = 3420256ULL * 4;         // bytes, 16B aligned
  const size_t MH_OFF = XH_OFF + (size_t)N_NODES * D * 2;  // +25.6 MB
  unsigned* xh = (unsigned*)((char*)d_ws + XH_OFF);
  unsigned* mh = (unsigned*)((char*)d_ws + MH_OFF);

  hipMemsetAsync(btail, 0, 800 * sizeof(int), stream);
  fuseA_k<<<CVTB + PBLK + PREPB, 256, 0, stream>>>(x, xh, ei, btail, part,
                                                   Wl, Wr, wt_g);
  p4c_k<<<NB2, 512, 0, stream>>>(part, btail, pd);
  gather2_k<<<12500, 256, 0, stream>>>(xh, part, pd, mh);
  fused_k<<<(TILES + WPB - 1) / WPB, 512, 0, stream>>>(xh, mh, (const unsigned*)wt_g, bl, out);
}

// Round 10
// 142.285 us; speedup vs baseline: 1.0723x; 1.0723x over previous
//
#include <hip/hip_runtime.h>
#include <hip/hip_bf16.h>

#define N_NODES 100000
#define N_EDGES 1600000
#define D 128
#define TILES (N_NODES / 16)   // 6250 row-tiles of 16
#define WPB 8                  // waves per block in fused kernel
#define NB2 782                // buckets of 128 nodes (ceil(100000/128))
#define NPB2 128               // nodes per bucket
#define CAP 4096               // edge capacity per bucket (mean 2046)
#define EPB 8192               // edges per partition block
#define PBLK 196               // ceil(1600000/8192)
#define CVTB 6250              // cvt blocks in cvtw_k
#define PREPB 128              // prepw blocks in cvtw_k

typedef __attribute__((ext_vector_type(4))) float f32x4;
typedef __attribute__((ext_vector_type(8))) short short8;
typedef __attribute__((ext_vector_type(4))) unsigned int u32x4;
typedef __attribute__((ext_vector_type(2))) unsigned int u32x2;

// f32 -> bf16 round-to-nearest-even
static __device__ __forceinline__ unsigned short f2bf(float f) {
  unsigned u = __float_as_uint(f);
  u += 0x7fffu + ((u >> 16) & 1u);
  return (unsigned short)(u >> 16);
}

static __device__ __forceinline__ void acc4(u32x2 u, float& a0, float& a1,
                                            float& a2, float& a3) {
  a0 += __uint_as_float(u[0] << 16);
  a1 += __uint_as_float(u[0] & 0xffff0000u);
  a2 += __uint_as_float(u[1] << 16);
  a3 += __uint_as_float(u[1] & 0xffff0000u);
}

// ---- cvtw: cvt (x->bf16) + prepw (W prep), disjoint block ranges ----
__global__ __launch_bounds__(256) void cvtw_k(const float* __restrict__ x,
                                              unsigned* __restrict__ xh,
                                              const float* __restrict__ Wl,
                                              const float* __restrict__ Wr,
                                              unsigned short* __restrict__ wt_g) {
  int t = threadIdx.x;
  if (blockIdx.x < CVTB) {
    size_t i = (size_t)blockIdx.x * 256 + t;
    const f32x4* p = (const f32x4*)(x + i * 8);
    f32x4 v0 = p[0], v1 = p[1];
    u32x4 o;
    o[0] = ((unsigned)f2bf(v0[1]) << 16) | f2bf(v0[0]);
    o[1] = ((unsigned)f2bf(v0[3]) << 16) | f2bf(v0[2]);
    o[2] = ((unsigned)f2bf(v1[1]) << 16) | f2bf(v1[0]);
    o[3] = ((unsigned)f2bf(v1[3]) << 16) | f2bf(v1[2]);
    *(u32x4*)(xh + i * 4) = o;
    return;
  }
  // prepw: W -> bf16 in physical swizzled layout
  int i = (blockIdx.x - CVTB) * 256 + t;  // 0..32767
  int k = i >> 7, c = i & 127;
  float w = (k < 128) ? Wl[k * 128 + c] : Wr[(k - 128) * 128 + c];
  int phys = (k >> 3) ^ (c & 7);
  wt_g[c * 256 + (phys << 3) + (k & 7)] = f2bf(w);
}

// ---- p1h: per-(block,bucket) histogram, NO global atomics ----
__global__ __launch_bounds__(256) void p1h_k(const int* __restrict__ ei,
                                             int* __restrict__ hist) {
  __shared__ int bh[NB2];
  int t = threadIdx.x;
  for (int i = t; i < NB2; i += 256) bh[i] = 0;
  __syncthreads();
  int base = blockIdx.x * EPB;
  int end = min(base + EPB, N_EDGES);
  for (int i = base + t; i < end; i += 256)
    atomicAdd(&bh[ei[N_EDGES + i] >> 7], 1);
  __syncthreads();
  for (int i = t; i < NB2; i += 256) hist[blockIdx.x * NB2 + i] = bh[i];
}

// ---- scanb: per-bucket exclusive scan over the 196 block counts (in place),
// and bucket totals ----
__global__ __launch_bounds__(256) void scanb_k(int* __restrict__ hist,
                                               int* __restrict__ bcnt) {
  __shared__ int s[256];
  int b = blockIdx.x, t = threadIdx.x;
  int v = (t < PBLK) ? hist[t * NB2 + b] : 0;
  s[t] = v;
  __syncthreads();
  for (int o = 1; o < 256; o <<= 1) {
    int u = (t >= o) ? s[t - o] : 0;
    __syncthreads();
    s[t] += u;
    __syncthreads();
  }
  if (t < PBLK) hist[t * NB2 + b] = s[t] - v;  // exclusive base (relative)
  if (t == 0) bcnt[b] = min(s[255], CAP);
}

// ---- p3c: scatter edges into bucket regions using exact precomputed bases;
// only LDS atomics. code = (dst & 127) << 17 | src ----
__global__ __launch_bounds__(256) void p3c_k(const int* __restrict__ ei,
                                             const int* __restrict__ hist,
                                             unsigned* __restrict__ part) {
  __shared__ int lbase[NB2], lcur[NB2];
  int t = threadIdx.x, blk = blockIdx.x;
  for (int i = t; i < NB2; i += 256) {
    lbase[i] = hist[blk * NB2 + i];
    lcur[i] = 0;
  }
  __syncthreads();
  int base = blk * EPB;
  int end = min(base + EPB, N_EDGES);
  for (int i = base + t; i < end; i += 256) {
    int dst = ei[N_EDGES + i];
    int src = ei[i];
    int b = dst >> 7;
    int rel = lbase[b] + atomicAdd(&lcur[b], 1);
    if (rel < CAP)
      part[(size_t)b * CAP + rel] =
          ((unsigned)(dst & (NPB2 - 1)) << 17) | (unsigned)src;
  }
}

// ---- p4c: per-bucket CSR build. Stages codes in LDS, writes per-node
// (beg,deg) and the CSR IN PLACE over the part region. ----
__global__ __launch_bounds__(512) void p4c_k(unsigned* __restrict__ part,
                                             const int* __restrict__ bcnt,
                                             int2* __restrict__ pd) {
  __shared__ unsigned s_codes[CAP];  // 16 KiB
  __shared__ int s_deg[NPB2], s_scan[NPB2], s_off[NPB2];
  int t = threadIdx.x, b = blockIdx.x;
  int ne = min(bcnt[b], CAP);
  unsigned* pp = part + (size_t)b * CAP;
  for (int i = t; i < ne; i += 512) s_codes[i] = pp[i];
  if (t < NPB2) s_deg[t] = 0;
  __syncthreads();
  for (int i = t; i < ne; i += 512) atomicAdd(&s_deg[s_codes[i] >> 17], 1);
  __syncthreads();
  if (t < NPB2) s_scan[t] = s_deg[t];
  __syncthreads();
  for (int o = 1; o < NPB2; o <<= 1) {  // inclusive scan over 128 counts
    int u = (t >= o && t < NPB2) ? s_scan[t - o] : 0;
    __syncthreads();
    if (t < NPB2) s_scan[t] += u;
    __syncthreads();
  }
  if (t < NPB2) {
    int deg = s_deg[t];
    int ex = s_scan[t] - deg;
    s_off[t] = ex;
    int node = b * NPB2 + t;
    if (node < N_NODES) {
      int2 v;
      v.x = b * CAP + ex;
      v.y = deg;
      pd[node] = v;
    }
  }
  __syncthreads();
  for (int i = t; i < ne; i += 512) {
    unsigned c = s_codes[i];
    int pos = atomicAdd(&s_off[c >> 17], 1);
    pp[pos] = c & 0x1FFFFu;  // csr overwrites part region (staged in LDS)
  }
}

// ---- Gather: 2 nodes/wave, 32 lanes x 4 dims, 8-deep MLP ----
__global__ __launch_bounds__(256) void gather2_k(const unsigned* __restrict__ xh,
                                                 const unsigned* __restrict__ csr,
                                                 const int2* __restrict__ pd,
                                                 unsigned* __restrict__ mh) {
  int wid = (blockIdx.x * 256 + threadIdx.x) >> 6;
  int lane = threadIdx.x & 63;
  int half = lane >> 5, lh = lane & 31;
  int node = wid * 2 + half;
  if (node >= N_NODES) return;
  int2 v = pd[node];
  int base = v.x;
  int deg = v.y;
  float a0 = 0.f, a1 = 0.f, a2 = 0.f, a3 = 0.f;
  float b0 = 0.f, b1 = 0.f, b2 = 0.f, b3 = 0.f;
  for (int c = 0; c < deg; c += 32) {
    int rem = deg - c;
    int n = min(32, rem);
    int eidx = (lh < rem) ? (int)csr[base + c + lh] : 0;
    int j = 0;
    for (; j + 7 < n; j += 8) {
      int s0 = __shfl(eidx, j, 32);
      int s1 = __shfl(eidx, j + 1, 32);
      int s2 = __shfl(eidx, j + 2, 32);
      int s3 = __shfl(eidx, j + 3, 32);
      int s4 = __shfl(eidx, j + 4, 32);
      int s5 = __shfl(eidx, j + 5, 32);
      int s6 = __shfl(eidx, j + 6, 32);
      int s7 = __shfl(eidx, j + 7, 32);
      u32x2 u0 = *(const u32x2*)(xh + (size_t)s0 * 64 + lh * 2);
      u32x2 u1 = *(const u32x2*)(xh + (size_t)s1 * 64 + lh * 2);
      u32x2 u2 = *(const u32x2*)(xh + (size_t)s2 * 64 + lh * 2);
      u32x2 u3 = *(const u32x2*)(xh + (size_t)s3 * 64 + lh * 2);
      u32x2 u4 = *(const u32x2*)(xh + (size_t)s4 * 64 + lh * 2);
      u32x2 u5 = *(const u32x2*)(xh + (size_t)s5 * 64 + lh * 2);
      u32x2 u6 = *(const u32x2*)(xh + (size_t)s6 * 64 + lh * 2);
      u32x2 u7 = *(const u32x2*)(xh + (size_t)s7 * 64 + lh * 2);
      acc4(u0, a0, a1, a2, a3);
      acc4(u1, b0, b1, b2, b3);
      acc4(u2, a0, a1, a2, a3);
      acc4(u3, b0, b1, b2, b3);
      acc4(u4, a0, a1, a2, a3);
      acc4(u5, b0, b1, b2, b3);
      acc4(u6, a0, a1, a2, a3);
      acc4(u7, b0, b1, b2, b3);
    }
    for (; j + 3 < n; j += 4) {
      int s0 = __shfl(eidx, j, 32);
      int s1 = __shfl(eidx, j + 1, 32);
      int s2 = __shfl(eidx, j + 2, 32);
      int s3 = __shfl(eidx, j + 3, 32);
      u32x2 u0 = *(const u32x2*)(xh + (size_t)s0 * 64 + lh * 2);
      u32x2 u1 = *(const u32x2*)(xh + (size_t)s1 * 64 + lh * 2);
      u32x2 u2 = *(const u32x2*)(xh + (size_t)s2 * 64 + lh * 2);
      u32x2 u3 = *(const u32x2*)(xh + (size_t)s3 * 64 + lh * 2);
      acc4(u0, a0, a1, a2, a3);
      acc4(u1, b0, b1, b2, b3);
      acc4(u2, a0, a1, a2, a3);
      acc4(u3, b0, b1, b2, b3);
    }
    for (; j < n; j++) {
      int s0 = __shfl(eidx, j, 32);
      u32x2 u0 = *(const u32x2*)(xh + (size_t)s0 * 64 + lh * 2);
      acc4(u0, a0, a1, a2, a3);
    }
  }
  float inv = 1.0f / fmaxf((float)deg, 1.0f);
  a0 = (a0 + b0) * inv;
  a1 = (a1 + b1) * inv;
  a2 = (a2 + b2) * inv;
  a3 = (a3 + b3) * inv;
  u32x2 o;
  o[0] = ((unsigned)f2bf(a1) << 16) | f2bf(a0);
  o[1] = ((unsigned)f2bf(a3) << 16) | f2bf(a2);
  *(u32x2*)(mh + (size_t)node * 64 + lh * 2) = o;
}

// ---- Fused: out = normalize( [mean | x] @ [W_l; W_r] + b_l ), bf16 MFMA ----
__global__ __launch_bounds__(512) void fused_k(
    const unsigned* __restrict__ xh, const unsigned* __restrict__ mh,
    const unsigned* __restrict__ wt_g, const float* __restrict__ bl,
    float* __restrict__ out) {
  __shared__ unsigned Wt[16384];  // 64 KiB as u32 (32768 bf16)

  int tid = threadIdx.x;
  {
    const u32x4* src = (const u32x4*)wt_g;
    u32x4* dst = (u32x4*)Wt;
    #pragma unroll
    for (int it = 0; it < 8; it++) dst[it * 512 + tid] = src[it * 512 + tid];
  }
  __syncthreads();

  int tile = blockIdx.x * WPB + (tid >> 6);
  if (tile >= TILES) return;
  int lane = tid & 63;
  int c0 = lane & 15;  // A-row within tile / D-column-within-16
  int g = lane >> 4;   // k-group selector
  int row0 = tile * 16;
  const unsigned short* Wt16 = (const unsigned short*)Wt;

  f32x4 acc[8];
  #pragma unroll
  for (int ct = 0; ct < 8; ct++)
    for (int j = 0; j < 4; j++) acc[ct][j] = 0.0f;

  #pragma unroll
  for (int kf = 0; kf < 8; kf++) {
    int koff = (kf & 3) * 32 + g * 8;
    const unsigned short* a_src = (const unsigned short*)((kf < 4) ? mh : xh);
    short8 af = *(const short8*)(a_src + (size_t)(row0 + c0) * D + koff);
    #pragma unroll
    for (int ct = 0; ct < 8; ct++) {
      int c = ct * 16 + c0;
      short8 bf = *(const short8*)&Wt16[c * 256 + ((((kf << 2) + g) ^ (c & 7)) << 3)];
      acc[ct] = __builtin_amdgcn_mfma_f32_16x16x32_bf16(af, bf, acc[ct], 0, 0, 0);
    }
  }

  float ss[4] = {0.f, 0.f, 0.f, 0.f};
  #pragma unroll
  for (int ct = 0; ct < 8; ct++) {
    float bias = bl[ct * 16 + c0];
    #pragma unroll
    for (int j = 0; j < 4; j++) {
      float v = acc[ct][j] + bias;
      acc[ct][j] = v;
      ss[j] += v * v;
    }
  }
  #pragma unroll
  for (int j = 0; j < 4; j++) {
    float s = ss[j];
    s += __shfl_xor(s, 1);
    s += __shfl_xor(s, 2);
    s += __shfl_xor(s, 4);
    s += __shfl_xor(s, 8);
    ss[j] = 1.0f / fmaxf(sqrtf(s), 1e-12f);
  }
  #pragma unroll
  for (int ct = 0; ct < 8; ct++) {
    #pragma unroll
    for (int j = 0; j < 4; j++) {
      out[(size_t)(row0 + g * 4 + j) * D + ct * 16 + c0] = acc[ct][j] * ss[j];
    }
  }
}

extern "C" void kernel_launch(void* const* d_in, const int* in_sizes, int n_in,
                              void* d_out, int out_size, void* d_ws, size_t ws_size,
                              hipStream_t stream) {
  const float* x  = (const float*)d_in[0];
  const int*   ei = (const int*)d_in[1];
  const float* Wl = (const float*)d_in[2];
  const float* bl = (const float*)d_in[3];
  const float* Wr = (const float*)d_in[4];
  float* out = (float*)d_out;

  // Workspace layout (int elements)
  int* w = (int*)d_ws;
  int* hist = w;                                 // 196*782 = 153272 (pad 153600)
  int* bcnt = w + 153600;                        // 782 (pad 800)
  int2* pd = (int2*)(w + 154400);                // 100000 int2 = 200000 ints
  unsigned* part = (unsigned*)(w + 354400);      // 782*4096 = 3203072 (12.8 MB)
  unsigned short* wt_g = (unsigned short*)(w + 3557472);  // 32768 u16
  const size_t XH_OFF = 3573856ULL * 4;          // bytes, 16B aligned
  const size_t MH_OFF = XH_OFF + (size_t)N_NODES * D * 2;  // +25.6 MB
  unsigned* xh = (unsigned*)((char*)d_ws + XH_OFF);
  unsigned* mh = (unsigned*)((char*)d_ws + MH_OFF);

  cvtw_k<<<CVTB + PREPB, 256, 0, stream>>>(x, xh, Wl, Wr, wt_g);
  p1h_k<<<PBLK, 256, 0, stream>>>(ei, hist);
  scanb_k<<<NB2, 256, 0, stream>>>(hist, bcnt);
  p3c_k<<<PBLK, 256, 0, stream>>>(ei, hist, part);
  p4c_k<<<NB2, 512, 0, stream>>>(part, bcnt, pd);
  gather2_k<<<12500, 256, 0, stream>>>(xh, part, pd, mh);
  fused_k<<<(TILES + WPB - 1) / WPB, 512, 0, stream>>>(xh, mh, (const unsigned*)wt_g, bl, out);
}